// Round 3
// baseline (535.797 us; speedup 1.0000x reference)
//
#include <hip/hip_runtime.h>
#include <hip/hip_bf16.h>
#include <stdint.h>

// ---------- helpers ----------
__device__ __forceinline__ uint16_t f2bf(float f) {
    union { float f; uint32_t u; } c; c.f = f;
    uint32_t u = c.u;
    return (uint16_t)((u + 0x7FFFu + ((u >> 16) & 1u)) >> 16);  // RNE
}
__device__ __forceinline__ uint32_t pack2(float a, float b) {
    return (uint32_t)f2bf(a) | ((uint32_t)f2bf(b) << 16);
}

typedef __bf16 bf16x8 __attribute__((ext_vector_type(8)));
typedef float  f32x4  __attribute__((ext_vector_type(4)));

#define GLOAD_LDS16(g, l) __builtin_amdgcn_global_load_lds( \
    (const __attribute__((address_space(1))) void*)(g),     \
    (__attribute__((address_space(3))) void*)(l), 16, 0, 0)

// ---------- Kernel 1: LayerNorm, fp32 in -> bf16 out. One block per row. ----------
// D = 2048 = 256 threads * 8 elems. Thread t owns elements [8t, 8t+8).
__global__ __launch_bounds__(256) void ln_kernel(
    const float* __restrict__ x, const float* __restrict__ gw,
    const float* __restrict__ gb, uint16_t* __restrict__ y, int D)
{
    const int t = threadIdx.x;
    const size_t row = blockIdx.x;
    const float4* xr = (const float4*)(x + row * (size_t)D);
    float4 v0 = xr[2 * t], v1 = xr[2 * t + 1];

    float s  = v0.x + v0.y + v0.z + v0.w + v1.x + v1.y + v1.z + v1.w;
    float ss = v0.x * v0.x + v0.y * v0.y + v0.z * v0.z + v0.w * v0.w
             + v1.x * v1.x + v1.y * v1.y + v1.z * v1.z + v1.w * v1.w;
#pragma unroll
    for (int off = 32; off > 0; off >>= 1) {
        s  += __shfl_down(s, off);
        ss += __shfl_down(ss, off);
    }
    __shared__ float red[10];
    const int wave = t >> 6, lane = t & 63;
    if (lane == 0) { red[wave] = s; red[4 + wave] = ss; }
    __syncthreads();
    if (t == 0) {
        float S  = red[0] + red[1] + red[2] + red[3];
        float SS = red[4] + red[5] + red[6] + red[7];
        float mu = S / (float)D;
        float var = SS / (float)D - mu * mu;
        red[8] = mu;
        red[9] = rsqrtf(var + 1e-5f);
    }
    __syncthreads();
    const float mu = red[8], rstd = red[9];

    const float4* wr = (const float4*)gw;
    const float4* br = (const float4*)gb;
    float4 w0 = wr[2 * t], w1 = wr[2 * t + 1];
    float4 b0 = br[2 * t], b1 = br[2 * t + 1];

    uint4 ov;
    ov.x = pack2((v0.x - mu) * rstd * w0.x + b0.x, (v0.y - mu) * rstd * w0.y + b0.y);
    ov.y = pack2((v0.z - mu) * rstd * w0.z + b0.z, (v0.w - mu) * rstd * w0.w + b0.w);
    ov.z = pack2((v1.x - mu) * rstd * w1.x + b1.x, (v1.y - mu) * rstd * w1.y + b1.y);
    ov.w = pack2((v1.z - mu) * rstd * w1.z + b1.z, (v1.w - mu) * rstd * w1.w + b1.w);
    ((uint4*)(y + row * (size_t)D))[t] = ov;
}

// ---------- Kernel 2: weights fp32 -> bf16, concat [Wq;Wk;Wv] -> Wcat[6144*2048] ----------
__global__ __launch_bounds__(256) void wcvt_kernel(
    const float* __restrict__ wq, const float* __restrict__ wk,
    const float* __restrict__ wv, uint16_t* __restrict__ out)
{
    const size_t i = ((size_t)blockIdx.x * 256 + threadIdx.x) * 8;
    const int which = (int)(i >> 22);            // 2048*2048 = 2^22 per matrix
    const float* src = (which == 0) ? wq : (which == 1) ? wk : wv;
    const size_t off = i & ((1u << 22) - 1);
    float4 a = *(const float4*)(src + off);
    float4 b = *(const float4*)(src + off + 4);
    uint4 ov;
    ov.x = pack2(a.x, a.y);
    ov.y = pack2(a.z, a.w);
    ov.z = pack2(b.x, b.y);
    ov.w = pack2(b.z, b.w);
    *(uint4*)(out + i) = ov;
}

// ---------- Kernel 3: C[M,N] = A[M,K] * Wcat[N,K]^T + bias, bf16 MFMA, fp32 out ----------
// m97 structure: 128x128 tile, BK=32, 4 waves (2x2 of 64x64), 16x16x32 MFMA,
// global_load_lds width=16 staging (unpadded LDS, wave-uniform base + lane*16B).
__global__ __launch_bounds__(256) void qkv_gemm(
    const uint16_t* __restrict__ A, const uint16_t* __restrict__ W,
    const float* __restrict__ Bq, const float* __restrict__ Bk,
    const float* __restrict__ Bv,
    float* __restrict__ C, int M, int N, int K)
{
    __shared__ uint16_t As[128 * 32];
    __shared__ uint16_t Bs[128 * 32];

    const int t = threadIdx.x, wave = t >> 6, lane = t & 63;
    const int nb = blockIdx.x, mb = blockIdx.y;
    const int ncol0 = nb * 128;          // global output column base = Wcat row base

    // staging: chunk c = 16 rows x 32 cols = 512 elems = 64 lanes * 8 elems (16B)
    const int c0 = wave * 2, c1 = wave * 2 + 1;
    const int lrow = lane >> 2, lk = (lane & 3) * 8;
    const uint16_t* ga0 = A + (size_t)(mb * 128 + c0 * 16 + lrow) * K + lk;
    const uint16_t* ga1 = A + (size_t)(mb * 128 + c1 * 16 + lrow) * K + lk;
    const uint16_t* gb0 = W + (size_t)(ncol0 + c0 * 16 + lrow) * K + lk;
    const uint16_t* gb1 = W + (size_t)(ncol0 + c1 * 16 + lrow) * K + lk;
    uint16_t* la0 = &As[c0 * 512];
    uint16_t* la1 = &As[c1 * 512];
    uint16_t* lb0 = &Bs[c0 * 512];
    uint16_t* lb1 = &Bs[c1 * 512];

    f32x4 acc[4][4] = {};

    const int wm = (wave >> 1) * 64, wn = (wave & 1) * 64;
    const int fr = lane & 15, fq = (lane >> 4) * 8;

    for (int kt = 0; kt < K; kt += 32) {
        GLOAD_LDS16(ga0, la0);
        GLOAD_LDS16(ga1, la1);
        GLOAD_LDS16(gb0, lb0);
        GLOAD_LDS16(gb1, lb1);
        ga0 += 32; ga1 += 32; gb0 += 32; gb1 += 32;
        __syncthreads();   // drains vmcnt -> LDS tiles valid

        bf16x8 af[4], bfv[4];
#pragma unroll
        for (int i = 0; i < 4; ++i)
            af[i] = *(const bf16x8*)&As[(wm + i * 16 + fr) * 32 + fq];
#pragma unroll
        for (int j = 0; j < 4; ++j)
            bfv[j] = *(const bf16x8*)&Bs[(wn + j * 16 + fr) * 32 + fq];
#pragma unroll
        for (int i = 0; i < 4; ++i)
#pragma unroll
            for (int j = 0; j < 4; ++j)
                acc[i][j] = __builtin_amdgcn_mfma_f32_16x16x32_bf16(
                    af[i], bfv[j], acc[i][j], 0, 0, 0);
        __syncthreads();   // protect LDS before next staging
    }

    // epilogue: C/D layout row(m) = (lane>>4)*4+reg, col(n) = lane&15. fp32 stores.
    const int orow0 = mb * 128 + wm + (lane >> 4) * 4;
#pragma unroll
    for (int j = 0; j < 4; ++j) {
        const int colg = ncol0 + wn + j * 16 + fr;      // global col in [0, 6144)
        const int which = colg >> 11;
        const float* bp = (which == 0) ? Bq : (which == 1) ? Bk : Bv;
        const float bj = bp[colg & 2047];
#pragma unroll
        for (int i = 0; i < 4; ++i) {
            const int r0 = orow0 + i * 16;
#pragma unroll
            for (int r = 0; r < 4; ++r) {
                C[(size_t)(r0 + r) * N + colg] = acc[i][j][r] + bj;
            }
        }
    }
}

extern "C" void kernel_launch(void* const* d_in, const int* in_sizes, int n_in,
                              void* d_out, int out_size, void* d_ws, size_t ws_size,
                              hipStream_t stream) {
    const float* x  = (const float*)d_in[0];
    const float* nw = (const float*)d_in[1];
    const float* nb = (const float*)d_in[2];
    const float* wq = (const float*)d_in[3];
    const float* bq = (const float*)d_in[4];
    const float* wk = (const float*)d_in[5];
    const float* bk = (const float*)d_in[6];
    const float* wv = (const float*)d_in[7];
    const float* bv = (const float*)d_in[8];

    const int D = in_sizes[1];        // 2048
    const int M = in_sizes[0] / D;    // 8192 (B*S)
    const int N = 3 * D;              // 6144

    // ws layout: [normed bf16: M*D] [Wcat bf16: N*D]  (32 MB + 24 MB)
    uint16_t* normed = (uint16_t*)d_ws;
    uint16_t* wcat   = normed + (size_t)M * D;

    ln_kernel<<<M, 256, 0, stream>>>(x, nw, nb, normed, D);
    wcvt_kernel<<<((size_t)N * D) / (256 * 8), 256, 0, stream>>>(wq, wk, wv, wcat);
    dim3 grid(N / 128, M / 128);
    qkv_gemm<<<grid, 256, 0, stream>>>(normed, wcat, bq, bk, bv,
                                       (float*)d_out, M, N, D);
}